// Round 1
// baseline (172.774 us; speedup 1.0000x reference)
//
#include <hip/hip_runtime.h>
#include <math.h>

// ---------------- problem constants ----------------
#define NB 8          // batch
#define NM 16         // modes
#define NPH 8         // photons
#define NSTATES 12870 // C(16,8)
#define NSUB 256      // 2^NPH column subsets
#define OUTS 128
#define NTILES 824    // sum over classes of ceil(R/4)*ceil(C/4)
#define NSLOTS (NTILES*16) // 13184
#define NSGQ 16       // s-groups of 16 (partial-accumulation granularity)
#define SPH 16        // s per block (one DP phase per block)
#define NTG 4         // tile groups
#define TILES_PER_TG 206
#define NSPLIT 128    // split-K blocks in tail
#define KS2 101       // k-rows per tail block (128*101 >= 12870)

// ---------------- compile-time tables ----------------
struct Tables {
  int binom[17][9];
  unsigned char cls_masks[256]; // 8-bit masks sorted by (popcount, value)
  int cls_off[10];              // offsets into cls_masks per popcount
  int nt1[9], nt2[9];           // 4-tiles per dim per class
  int tile_off[10];
};

constexpr int cpopc(int x){ int c=0; while(x){ c += x & 1; x >>= 1; } return c; }

constexpr Tables make_tables(){
  Tables t{};
  for (int n=0;n<=16;n++)
    for (int k=0;k<=8;k++){
      if (k==0) t.binom[n][k]=1;
      else if (n==0) t.binom[n][k]=0;
      else t.binom[n][k]=t.binom[n-1][k-1]+t.binom[n-1][k];
    }
  int idx=0;
  for (int p=0;p<=8;p++){
    t.cls_off[p]=idx;
    for (int m=0;m<256;m++) if (cpopc(m)==p) t.cls_masks[idx++]=(unsigned char)m;
  }
  t.cls_off[9]=idx; // 256
  int toff=0;
  for (int c=0;c<=8;c++){
    int R=t.binom[8][c], C=t.binom[8][8-c];
    t.nt1[c]=(R+3)/4; t.nt2[c]=(C+3)/4;
    t.tile_off[c]=toff; toff += t.nt1[c]*t.nt2[c];
  }
  t.tile_off[9]=toff;
  return t;
}

constexpr Tables HTBL = make_tables();
static_assert(HTBL.tile_off[9]==NTILES, "tile count");
static_assert(HTBL.cls_off[9]==256, "mask count");
__device__ const Tables TBL = HTBL;

// next-pow2 shift for masks-per-level: C(8,p) = 1,8,28,56,70,56,28,8,1
__device__ const int LVL_SHIFT[9] = {0,3,5,6,7,6,5,3,0};

// ---------------- workspace layout (bytes) ----------------
#define WS_CNT   0                  // 4 B ticket counter (zeroed by k_fused blk 0)
#define WS_V     256                // [NB][NSUB][NM] float2 = 262144 B -> ends 262400
#define WS_BSUM  262400             // [NSPLIT][NB] float = 4096 B -> ends 266496
#define WS_PART  270336             // [NB][NSGQ][NSLOTS] float2 = 13500416 B -> ends 13770752
#define WS_POUT  13770752           // [NSPLIT][NB][OUTS] float = 524288 B -> ends 14295040

// ---------------- complex helpers ----------------
__device__ __forceinline__ float2 cmul(float2 a, float2 b){
  return make_float2(fmaf(a.x,b.x,-(a.y*b.y)), fmaf(a.x,b.y, a.y*b.x));
}
__device__ __forceinline__ void cmac(float2& acc, float2 a, float2 b){
  acc.x = fmaf(a.x, b.x, acc.x); acc.x = fmaf(-a.y, b.y, acc.x);
  acc.y = fmaf(a.x, b.y, acc.y); acc.y = fmaf(a.y, b.x, acc.y);
}

// ---------------- K1: fused setup + factorized Ryser main ----------------
// grid 512 = NB(8) x NSGQ(16) x NTG(4); 64 KB LDS -> 2 blocks/CU, 2 waves/SIMD.
// Prologue (unitaries, Uin, V-slice) runs redundantly per block using the
// P-table LDS as scratch (all scratch dead before DP init). Each block writes
// ONLY its own 16-s V slice to global and reads ONLY that slice back after a
// barrier (vmcnt drained at barrier; tg-twin blocks write bitwise-identical
// bytes, so the write race is benign).
__global__ __launch_bounds__(256) void k_fused(
    const float* __restrict__ x, const float* __restrict__ th1,
    const float* __restrict__ th2, const float* __restrict__ mr,
    const float* __restrict__ mi, char* ws)
{
  __shared__ float2 P1L[SPH][256];   // 32 KB
  __shared__ float2 P2L[SPH][256];   // 32 KB (total exactly 64 KB)
  int tid = threadIdx.x;
  int blk = blockIdx.x;
  int b = blk >> 6, rest = blk & 63, sgq = rest >> 2, tg = rest & 3;
  if (blk == 0 && tid == 0) *(int*)(ws + WS_CNT) = 0;  // ticket for k_tail

  float2* __restrict__ Vg = (float2*)(ws + WS_V);

  // prologue scratch aliases inside P tables (dead before DP init)
  float2 (*T1)[NM] = reinterpret_cast<float2(*)[NM]>(P1L[0]);
  float2 (*T2)[NM] = reinterpret_cast<float2(*)[NM]>(P1L[1]);
  float2 (*Am)[NM] = reinterpret_cast<float2(*)[NM]>(P1L[2]);
  float2 (*Bm)[NM] = reinterpret_cast<float2(*)[NM]>(P1L[3]);
  float2 (*EA)[NPH] = reinterpret_cast<float2(*)[NPH]>(P1L[4]);
  float2* UinP = P2L[0];   // [NM][NPH] = 128 entries
  float2* exP  = P2L[1];   // [NM]

  {
    int r = tid >> 4, cc = tid & 15;
    float sn, cs;
    sincosf(th1[r], &sn, &cs);
    float a = mr[0*256 + tid], bb = mi[0*256 + tid];   // M0[r][cc]
    T1[r][cc] = make_float2(cs*a - sn*bb, cs*bb + sn*a);
    sincosf(th2[r], &sn, &cs);
    float a2 = mr[2*256 + tid], b2 = mi[2*256 + tid];  // M2[r][cc]
    T2[r][cc] = make_float2(cs*a2 - sn*b2, cs*b2 + sn*a2);
    if (tid < NM){ float s2, c2; sincosf(x[b*NM + tid], &s2, &c2); exP[tid] = make_float2(c2, s2); }
  }
  __syncthreads();
  {
    int r = tid >> 4, cc = tid & 15;
    float2 accA = make_float2(0,0), accB = make_float2(0,0);
    for (int m=0;m<NM;m++){
      float2 m1 = make_float2(mr[1*256 + r*16+m], mi[1*256 + r*16+m]);
      cmac(accA, m1, T1[m][cc]);
      float2 m3 = make_float2(mr[3*256 + r*16+m], mi[3*256 + r*16+m]);
      cmac(accB, m3, T2[m][cc]);
    }
    Am[r][cc] = accA; Bm[r][cc] = accB;   // rows 2,3: disjoint from T rows 0,1
  }
  __syncthreads();
  if (tid < NM*NPH){ int m = tid >> 3, n = tid & 7; EA[m][n] = cmul(exP[m], Am[m][n]); }
  __syncthreads();
  if (tid < NM*NPH){
    int p = tid >> 3, n = tid & 7;
    float2 acc = make_float2(0,0);
    for (int m=0;m<NM;m++) cmac(acc, Bm[p][m], EA[m][n]);
    UinP[p*NPH + n] = acc;
  }
  __syncthreads();
  {
    // V[s][m] = sum over set bits j of s of Uin[m][j]; only our 16-s slice
    int sl = tid >> 4, m = tid & 15;
    int sg = sgq*SPH + sl;
    float2 a = make_float2(0,0);
    #pragma unroll
    for (int j=0;j<NPH;j++)
      if ((sg>>j)&1){ a.x += UinP[m*NPH+j].x; a.y += UinP[m*NPH+j].y; }
    Vg[b*(NSUB*NM) + sg*NM + m] = a;
  }

  // combine-thread tile masks (registers + const tables only)
  bool active = tid < TILES_PER_TG;
  int tile = tg + 4*tid;
  int t1v[4] = {0,0,0,0}, t2v[4] = {0,0,0,0};
  if (active){
    int c = 0;
    while (tile >= TBL.tile_off[c+1]) c++;
    int local = tile - TBL.tile_off[c];
    int n2 = TBL.nt2[c];
    int ti = local / n2, tj = local - ti*n2;
    int R = TBL.binom[8][c], C2 = TBL.binom[8][8-c];
    #pragma unroll
    for (int i=0;i<4;i++){ int r1 = ti*4+i; t1v[i] = (r1<R) ? (int)TBL.cls_masks[TBL.cls_off[c]+r1] : 0; }
    #pragma unroll
    for (int j=0;j<4;j++){ int r2 = tj*4+j; t2v[j] = (r2<C2) ? (int)TBL.cls_masks[TBL.cls_off[8-c]+r2] : 0; }
  }
  __syncthreads();   // drains Vg writes; prologue scratch dead from here

  // level-0 init (sign of Ryser folded into P1)
  if (tid < 2*SPH){
    int table = tid >> 4, s = tid & 15;
    float sg2 = 1.0f;
    if (table==0 && (__popc(sgq*SPH + s) & 1)) sg2 = -1.0f;
    (table ? P2L : P1L)[s][0] = make_float2(sg2, 0.0f);
  }
  __syncthreads();
  // DP build: P[t] = P[t & (t-1)] * V[row(lowbit)]
  for (int p=1;p<=8;p++){
    int nm = TBL.cls_off[p+1]-TBL.cls_off[p];
    int sh = LVL_SHIFT[p];
    int tot = (2*SPH) << sh;
    for (int q=tid; q<tot; q+=256){
      int mi2 = q & ((1<<sh)-1);
      if (mi2 < nm){
        int ts = q >> sh; int s = ts & 15, table = ts >> 4;
        int t = (int)TBL.cls_masks[TBL.cls_off[p]+mi2];
        int par = t & (t-1);
        int row = (__ffs(t)-1) + table*8;
        float2 pv = (table ? P2L : P1L)[s][par];
        float2 vv = Vg[b*(NSUB*NM) + (sgq*SPH+s)*NM + row];
        (table ? P2L : P1L)[s][t] = cmul(pv, vv);
      }
    }
    __syncthreads();
  }
  // 4x4 register-tiled combine (single phase)
  if (active){
    float2 acc[4][4] = {};
    for (int s=0;s<SPH;s++){
      float2 av[4], bv[4];
      #pragma unroll
      for (int i=0;i<4;i++) av[i] = P1L[s][t1v[i]];
      #pragma unroll
      for (int j=0;j<4;j++) bv[j] = P2L[s][t2v[j]];
      #pragma unroll
      for (int i=0;i<4;i++)
        #pragma unroll
        for (int j=0;j<4;j++) cmac(acc[i][j], av[i], bv[j]);
    }
    float2* dst = (float2*)(ws + WS_PART) + (size_t)(b*NSGQ + sgq)*NSLOTS + (size_t)tile*16;
    #pragma unroll
    for (int i=0;i<4;i++)
      #pragma unroll
      for (int j=0;j<4;j++) dst[i*4+j] = acc[i][j];
  }
}

// ---------------- K2: fused reduce + split-K gemm + last-block final -------
// NSPLIT blocks x 256 threads. Each block: (A) rank its k-range -> slots,
// (B) probs for all 8 b into LDS, (C) per-b partial sums -> bsum,
// (D) gemm partials -> pout, (E) last block (atomic ticket) normalizes + bias.
__global__ __launch_bounds__(256) void k_tail(
    const float* __restrict__ wgt, const float* __restrict__ bias,
    const int* __restrict__ rows, char* ws, float* __restrict__ out)
{
  __shared__ float lprob[NB][104];
  __shared__ int sslot[104];
  __shared__ float tsumL[NB];
  __shared__ int lastflag;
  int tid = threadIdx.x;
  int blk = blockIdx.x;
  int kb = blk * KS2;
  int ke = min(NSTATES, kb + KS2);
  int cnt = ke - kb;

  // (A) state k -> part slot (combinadic rank, same math as old tile map)
  for (int kk = tid; kk < cnt; kk += 256){
    int k = kb + kk;
    int t1 = 0, t2 = 0;
    #pragma unroll
    for (int i=0;i<NPH;i++){
      int rr = rows[k*NPH+i];
      if (rr < 8) t1 |= 1 << rr; else t2 |= 1 << (rr-8);
    }
    int c1 = __popc(t1);
    int rk1 = 0, ca = 0;
    #pragma unroll
    for (int bb=0;bb<8;bb++) if ((t1>>bb)&1){ ca++; rk1 += TBL.binom[bb][ca]; }
    int rk2 = 0; ca = 0;
    #pragma unroll
    for (int bb=0;bb<8;bb++) if ((t2>>bb)&1){ ca++; rk2 += TBL.binom[bb][ca]; }
    int tile = TBL.tile_off[c1] + (rk1>>2)*TBL.nt2[c1] + (rk2>>2);
    sslot[kk] = tile*16 + (((rk1&3)<<2) | (rk2&3));
  }
  __syncthreads();

  // (B) probs for (b, kk) pairs
  const float2* __restrict__ part = (const float2*)(ws + WS_PART);
  for (int idx = tid; idx < NB*cnt; idx += 256){
    int b = idx & 7, kk = idx >> 3;
    int slot = sslot[kk];
    float2 amp = make_float2(0,0);
    #pragma unroll
    for (int g=0; g<NSGQ; g++){
      float2 v = part[(size_t)(b*NSGQ + g)*NSLOTS + slot];
      amp.x += v.x; amp.y += v.y;
    }
    lprob[b][kk] = fmaf(amp.x, amp.x, amp.y*amp.y);
  }
  __syncthreads();

  // (C) per-b partial sums of this k-range
  float* bsum = (float*)(ws + WS_BSUM);
  {
    int b = tid >> 5, l = tid & 31;
    float v = 0.0f;
    for (int kk = l; kk < cnt; kk += 32) v += lprob[b][kk];
    #pragma unroll
    for (int off=16; off>0; off>>=1) v += __shfl_down(v, off, 32);
    if (l == 0) bsum[blk*NB + b] = v;
  }

  // (D) unnormalized gemm partials
  float* pout = (float*)(ws + WS_POUT);
  {
    int b = tid >> 5, col4 = tid & 31;
    float4 acc = make_float4(0.f, 0.f, 0.f, 0.f);
    #pragma unroll 8
    for (int kk=0; kk<cnt; kk++){
      float pf = lprob[b][kk];
      float4 wv = *(const float4*)(wgt + (size_t)(kb+kk)*OUTS + col4*4);
      acc.x = fmaf(pf, wv.x, acc.x);
      acc.y = fmaf(pf, wv.y, acc.y);
      acc.z = fmaf(pf, wv.z, acc.z);
      acc.w = fmaf(pf, wv.w, acc.w);
    }
    *(float4*)(pout + (size_t)blk*(NB*OUTS) + tid*4) = acc;
  }

  // (E) last-block finalization (threadfence-reduction pattern)
  __threadfence();
  __syncthreads();
  if (tid == 0) lastflag = (atomicAdd((int*)(ws + WS_CNT), 1) == NSPLIT-1) ? 1 : 0;
  __syncthreads();
  if (lastflag){
    __threadfence();
    if (tid < NB){
      float s = 0.0f;
      for (int j=0;j<NSPLIT;j++) s += bsum[j*NB + tid];
      tsumL[tid] = s;
    }
    __syncthreads();
    for (int idx = tid; idx < NB*OUTS; idx += 256){
      int b = idx >> 7, o = idx & 127;
      float acc = 0.0f;
      #pragma unroll 8
      for (int s2=0;s2<NSPLIT;s2++) acc += pout[(size_t)s2*(NB*OUTS) + b*OUTS + o];
      out[b*OUTS + o] = acc / tsumL[b] + bias[o];
    }
  }
}

// ---------------- launch ----------------
extern "C" void kernel_launch(void* const* d_in, const int* in_sizes, int n_in,
                              void* d_out, int out_size, void* d_ws, size_t ws_size,
                              hipStream_t stream) {
  const float* x    = (const float*)d_in[0];
  const float* th1  = (const float*)d_in[1];
  const float* th2  = (const float*)d_in[2];
  const float* mr   = (const float*)d_in[3];
  const float* mi   = (const float*)d_in[4];
  const float* wgt  = (const float*)d_in[5];
  const float* bias = (const float*)d_in[6];
  const int*   rows = (const int*)d_in[7];
  char* ws = (char*)d_ws;

  k_fused<<<NB*NSGQ*NTG, 256, 0, stream>>>(x, th1, th2, mr, mi, ws);
  k_tail<<<NSPLIT, 256, 0, stream>>>(wgt, bias, rows, ws, (float*)d_out);
}

// Round 2
// 164.693 us; speedup vs baseline: 1.0491x; 1.0491x over previous
//
#include <hip/hip_runtime.h>
#include <math.h>

// ---------------- problem constants ----------------
#define NB 8          // batch
#define NM 16         // modes
#define NPH 8         // photons
#define NSTATES 12870 // C(16,8)
#define NSUB 256      // 2^NPH column subsets
#define OUTS 128
#define NTILES 824    // sum over classes of ceil(R/4)*ceil(C/4)
#define NSLOTS (NTILES*16) // 13184
#define NSGQ 32       // s-groups of 8 (partial-accumulation granularity)
#define SPH 8         // s per block (one DP phase per block)
#define NTG 4         // tile groups
#define TILES_PER_TG 206
#define NRBLK 52      // ceil(NSLOTS/256) reduce blocks
#define NSPLIT 128    // split-K blocks in tail
#define KS2 101       // k-rows per tail block (128*101 >= 12870)

// ---------------- compile-time tables ----------------
struct Tables {
  int binom[17][9];
  unsigned char cls_masks[256]; // 8-bit masks sorted by (popcount, value)
  int cls_off[10];              // offsets into cls_masks per popcount
  int nt1[9], nt2[9];           // 4-tiles per dim per class
  int tile_off[10];
};

constexpr int cpopc(int x){ int c=0; while(x){ c += x & 1; x >>= 1; } return c; }

constexpr Tables make_tables(){
  Tables t{};
  for (int n=0;n<=16;n++)
    for (int k=0;k<=8;k++){
      if (k==0) t.binom[n][k]=1;
      else if (n==0) t.binom[n][k]=0;
      else t.binom[n][k]=t.binom[n-1][k-1]+t.binom[n-1][k];
    }
  int idx=0;
  for (int p=0;p<=8;p++){
    t.cls_off[p]=idx;
    for (int m=0;m<256;m++) if (cpopc(m)==p) t.cls_masks[idx++]=(unsigned char)m;
  }
  t.cls_off[9]=idx; // 256
  int toff=0;
  for (int c=0;c<=8;c++){
    int R=t.binom[8][c], C=t.binom[8][8-c];
    t.nt1[c]=(R+3)/4; t.nt2[c]=(C+3)/4;
    t.tile_off[c]=toff; toff += t.nt1[c]*t.nt2[c];
  }
  t.tile_off[9]=toff;
  return t;
}

constexpr Tables HTBL = make_tables();
static_assert(HTBL.tile_off[9]==NTILES, "tile count");
static_assert(HTBL.cls_off[9]==256, "mask count");
__device__ const Tables TBL = HTBL;

// next-pow2 shift for masks-per-level: C(8,p) = 1,8,28,56,70,56,28,8,1
__device__ const int LVL_SHIFT[9] = {0,3,5,6,7,6,5,3,0};

// ---------------- workspace layout (bytes) ----------------
#define WS_CNT   0                  // 4 B ticket counter (zeroed by k_fused blk 0)
#define WS_PROBS 256                // [NB][NSLOTS] float = 421888 B -> ends 422144
#define WS_BSUM  425984             // [NSPLIT][NB] float = 4096 B -> ends 430080
#define WS_POUT  430080             // [NSPLIT][NB][OUTS] float = 524288 B -> ends 954368
#define WS_PART  1048576            // [NB][NSGQ][NSLOTS] float2 = 27001856 B

// ---------------- complex helpers ----------------
__device__ __forceinline__ float2 cmul(float2 a, float2 b){
  return make_float2(fmaf(a.x,b.x,-(a.y*b.y)), fmaf(a.x,b.y, a.y*b.x));
}
__device__ __forceinline__ void cmac(float2& acc, float2 a, float2 b){
  acc.x = fmaf(a.x, b.x, acc.x); acc.x = fmaf(-a.y, b.y, acc.x);
  acc.y = fmaf(a.x, b.y, acc.y); acc.y = fmaf(a.y, b.x, acc.y);
}

// ---------------- K1: fused setup + factorized Ryser main ----------------
// grid 1024 = NB(8) x NSGQ(32) x NTG(4); ~33 KB LDS -> 4 blocks/CU (4 waves/SIMD).
// Prologue (unitaries, Uin, V-slice) runs redundantly per block in LDS scratch
// aliased over the P tables (all scratch dead before DP init). The V slice for
// this block's 8 s-values lives in LDS (VL) -> the DP inner loop has NO global
// memory traffic at all.
__global__ __launch_bounds__(256, 4) void k_fused(
    const float* __restrict__ x, const float* __restrict__ th1,
    const float* __restrict__ th2, const float* __restrict__ mr,
    const float* __restrict__ mi, char* ws)
{
  __shared__ float2 P1L[SPH][256];   // 16 KB
  __shared__ float2 P2L[SPH][256];   // 16 KB
  __shared__ float2 VL[SPH][NM];     // 1 KB  (V slice for this block's 8 s)
  int tid = threadIdx.x;
  int blk = blockIdx.x;
  int b = blk >> 7, rest = blk & 127, sg = rest >> 2, tg = rest & 3;
  if (blk == 0 && tid == 0) *(int*)(ws + WS_CNT) = 0;  // ticket for k_tail

  // prologue scratch aliases inside P tables (dead before DP init)
  float2 (*T1)[NM] = reinterpret_cast<float2(*)[NM]>(P1L[0]);
  float2 (*T2)[NM] = reinterpret_cast<float2(*)[NM]>(P1L[1]);
  float2 (*Am)[NM] = reinterpret_cast<float2(*)[NM]>(P1L[2]);
  float2 (*Bm)[NM] = reinterpret_cast<float2(*)[NM]>(P1L[3]);
  float2 (*EA)[NPH] = reinterpret_cast<float2(*)[NPH]>(P1L[4]);
  float2* UinP = P2L[0];   // [NM][NPH] = 128 entries
  float2* exP  = P2L[1];   // [NM]

  {
    int r = tid >> 4, cc = tid & 15;
    float sn, cs;
    sincosf(th1[r], &sn, &cs);
    float a = mr[0*256 + tid], bb = mi[0*256 + tid];   // M0[r][cc]
    T1[r][cc] = make_float2(cs*a - sn*bb, cs*bb + sn*a);
    sincosf(th2[r], &sn, &cs);
    float a2 = mr[2*256 + tid], b2 = mi[2*256 + tid];  // M2[r][cc]
    T2[r][cc] = make_float2(cs*a2 - sn*b2, cs*b2 + sn*a2);
    if (tid < NM){ float s2, c2; sincosf(x[b*NM + tid], &s2, &c2); exP[tid] = make_float2(c2, s2); }
  }
  __syncthreads();
  {
    int r = tid >> 4, cc = tid & 15;
    float2 accA = make_float2(0,0), accB = make_float2(0,0);
    for (int m=0;m<NM;m++){
      float2 m1 = make_float2(mr[1*256 + r*16+m], mi[1*256 + r*16+m]);
      cmac(accA, m1, T1[m][cc]);
      float2 m3 = make_float2(mr[3*256 + r*16+m], mi[3*256 + r*16+m]);
      cmac(accB, m3, T2[m][cc]);
    }
    Am[r][cc] = accA; Bm[r][cc] = accB;   // rows 2,3: disjoint from T rows 0,1
  }
  __syncthreads();
  if (tid < NM*NPH){ int m = tid >> 3, n = tid & 7; EA[m][n] = cmul(exP[m], Am[m][n]); }
  __syncthreads();
  if (tid < NM*NPH){
    int p = tid >> 3, n = tid & 7;
    float2 acc = make_float2(0,0);
    for (int m=0;m<NM;m++) cmac(acc, Bm[p][m], EA[m][n]);
    UinP[p*NPH + n] = acc;
  }
  __syncthreads();
  if (tid < SPH*NM){
    // V[s][m] = sum over set bits j of s of Uin[m][j]; only our 8-s slice, in LDS
    int sl = tid >> 4, m = tid & 15;
    int sgl = sg*SPH + sl;
    float2 a = make_float2(0,0);
    #pragma unroll
    for (int j=0;j<NPH;j++)
      if ((sgl>>j)&1){ a.x += UinP[m*NPH+j].x; a.y += UinP[m*NPH+j].y; }
    VL[sl][m] = a;
  }

  // combine-thread tile masks (registers + const tables only)
  bool active = tid < TILES_PER_TG;
  int tile = tg + 4*tid;
  int t1v[4] = {0,0,0,0}, t2v[4] = {0,0,0,0};
  if (active){
    int c = 0;
    while (tile >= TBL.tile_off[c+1]) c++;
    int local = tile - TBL.tile_off[c];
    int n2 = TBL.nt2[c];
    int ti = local / n2, tj = local - ti*n2;
    int R = TBL.binom[8][c], C2 = TBL.binom[8][8-c];
    #pragma unroll
    for (int i=0;i<4;i++){ int r1 = ti*4+i; t1v[i] = (r1<R) ? (int)TBL.cls_masks[TBL.cls_off[c]+r1] : 0; }
    #pragma unroll
    for (int j=0;j<4;j++){ int r2 = tj*4+j; t2v[j] = (r2<C2) ? (int)TBL.cls_masks[TBL.cls_off[8-c]+r2] : 0; }
  }
  __syncthreads();   // VL ready; prologue scratch dead from here

  // level-0 init (sign of Ryser folded into P1)
  if (tid < 2*SPH){
    int table = tid >> 3, s = tid & 7;
    float sg2 = 1.0f;
    if (table==0 && (__popc(sg*SPH + s) & 1)) sg2 = -1.0f;
    (table ? P2L : P1L)[s][0] = make_float2(sg2, 0.0f);
  }
  __syncthreads();
  // DP build: P[t] = P[t & (t-1)] * V[row(lowbit)] -- all LDS
  for (int p=1;p<=8;p++){
    int nm = TBL.cls_off[p+1]-TBL.cls_off[p];
    int sh = LVL_SHIFT[p];
    int tot = (2*SPH) << sh;
    for (int q=tid; q<tot; q+=256){
      int mi2 = q & ((1<<sh)-1);
      if (mi2 < nm){
        int ts = q >> sh; int s = ts & 7, table = ts >> 3;
        int t = (int)TBL.cls_masks[TBL.cls_off[p]+mi2];
        int par = t & (t-1);
        int row = (__ffs(t)-1) + table*8;
        float2 pv = (table ? P2L : P1L)[s][par];
        float2 vv = VL[s][row];
        (table ? P2L : P1L)[s][t] = cmul(pv, vv);
      }
    }
    __syncthreads();
  }
  // 4x4 register-tiled combine (8 s)
  if (active){
    float2 acc[4][4] = {};
    for (int s=0;s<SPH;s++){
      float2 av[4], bv[4];
      #pragma unroll
      for (int i=0;i<4;i++) av[i] = P1L[s][t1v[i]];
      #pragma unroll
      for (int j=0;j<4;j++) bv[j] = P2L[s][t2v[j]];
      #pragma unroll
      for (int i=0;i<4;i++)
        #pragma unroll
        for (int j=0;j<4;j++) cmac(acc[i][j], av[i], bv[j]);
    }
    float2* dst = (float2*)(ws + WS_PART) + (size_t)(b*NSGQ + sg)*NSLOTS + (size_t)tile*16;
    #pragma unroll
    for (int i=0;i<4;i++)
      #pragma unroll
      for (int j=0;j<4;j++) dst[i*4+j] = acc[i][j];
  }
}

// ---------------- K2: slot-ordered coalesced reduce ----------------
// grid (NRBLK, NB) x 256. Sums part over the 32 s-groups (coalesced: slot is
// the fastest-varying index) -> probs_slot[b][slot]. Padding slots produce
// garbage but are never gathered (k_tail is k-driven). No barriers, no LDS.
__global__ __launch_bounds__(256) void k_reduce(char* ws)
{
  int slot = blockIdx.x*256 + threadIdx.x;
  if (slot >= NSLOTS) return;
  int b = blockIdx.y;
  const float2* __restrict__ part = (const float2*)(ws + WS_PART);
  float* __restrict__ probs = (float*)(ws + WS_PROBS);
  float2 amp = make_float2(0,0);
  #pragma unroll
  for (int g=0; g<NSGQ; g++){
    float2 v = part[(size_t)(b*NSGQ + g)*NSLOTS + slot];
    amp.x += v.x; amp.y += v.y;
  }
  probs[b*NSLOTS + slot] = fmaf(amp.x, amp.x, amp.y*amp.y);
}

// ---------------- K3: split-K gemm + last-block final ----------------
// NSPLIT blocks x 256 threads. (A) rank k-range -> slots from rows,
// (B) gather probs (L2-resident 422 KB) into LDS, (C) per-b partial sums,
// (D) gemm partials -> pout, (E) last block (atomic ticket) normalizes + bias.
__global__ __launch_bounds__(256) void k_tail(
    const float* __restrict__ wgt, const float* __restrict__ bias,
    const int* __restrict__ rows, char* ws, float* __restrict__ out)
{
  __shared__ float lprob[NB][104];
  __shared__ int sslot[104];
  __shared__ float tsumL[NB];
  __shared__ int lastflag;
  int tid = threadIdx.x;
  int blk = blockIdx.x;
  int kb = blk * KS2;
  int ke = min(NSTATES, kb + KS2);
  int cnt = ke - kb;

  // (A) state k -> slot (combinadic rank, same math as the producer side)
  for (int kk = tid; kk < cnt; kk += 256){
    int k = kb + kk;
    int t1 = 0, t2 = 0;
    #pragma unroll
    for (int i=0;i<NPH;i++){
      int rr = rows[k*NPH+i];
      if (rr < 8) t1 |= 1 << rr; else t2 |= 1 << (rr-8);
    }
    int c1 = __popc(t1);
    int rk1 = 0, ca = 0;
    #pragma unroll
    for (int bb=0;bb<8;bb++) if ((t1>>bb)&1){ ca++; rk1 += TBL.binom[bb][ca]; }
    int rk2 = 0; ca = 0;
    #pragma unroll
    for (int bb=0;bb<8;bb++) if ((t2>>bb)&1){ ca++; rk2 += TBL.binom[bb][ca]; }
    int tile = TBL.tile_off[c1] + (rk1>>2)*TBL.nt2[c1] + (rk2>>2);
    sslot[kk] = tile*16 + (((rk1&3)<<2) | (rk2&3));
  }
  __syncthreads();

  // (B) gather probs for (b, kk) pairs -- 4 B loads from L2-resident array
  const float* __restrict__ probs = (const float*)(ws + WS_PROBS);
  for (int idx = tid; idx < NB*cnt; idx += 256){
    int b = idx & 7, kk = idx >> 3;
    lprob[b][kk] = probs[b*NSLOTS + sslot[kk]];
  }
  __syncthreads();

  // (C) per-b partial sums of this k-range
  float* bsum = (float*)(ws + WS_BSUM);
  {
    int b = tid >> 5, l = tid & 31;
    float v = 0.0f;
    for (int kk = l; kk < cnt; kk += 32) v += lprob[b][kk];
    #pragma unroll
    for (int off=16; off>0; off>>=1) v += __shfl_down(v, off, 32);
    if (l == 0) bsum[blk*NB + b] = v;
  }

  // (D) unnormalized gemm partials
  float* pout = (float*)(ws + WS_POUT);
  {
    int b = tid >> 5, col4 = tid & 31;
    float4 acc = make_float4(0.f, 0.f, 0.f, 0.f);
    #pragma unroll 8
    for (int kk=0; kk<cnt; kk++){
      float pf = lprob[b][kk];
      float4 wv = *(const float4*)(wgt + (size_t)(kb+kk)*OUTS + col4*4);
      acc.x = fmaf(pf, wv.x, acc.x);
      acc.y = fmaf(pf, wv.y, acc.y);
      acc.z = fmaf(pf, wv.z, acc.z);
      acc.w = fmaf(pf, wv.w, acc.w);
    }
    *(float4*)(pout + (size_t)blk*(NB*OUTS) + tid*4) = acc;
  }

  // (E) last-block finalization (threadfence-reduction pattern)
  __threadfence();
  __syncthreads();
  if (tid == 0) lastflag = (atomicAdd((int*)(ws + WS_CNT), 1) == NSPLIT-1) ? 1 : 0;
  __syncthreads();
  if (lastflag){
    __threadfence();
    if (tid < NB){
      float s = 0.0f;
      for (int j=0;j<NSPLIT;j++) s += bsum[j*NB + tid];
      tsumL[tid] = s;
    }
    __syncthreads();
    for (int idx = tid; idx < NB*OUTS; idx += 256){
      int b = idx >> 7, o = idx & 127;
      float acc = 0.0f;
      #pragma unroll 8
      for (int s2=0;s2<NSPLIT;s2++) acc += pout[(size_t)s2*(NB*OUTS) + b*OUTS + o];
      out[b*OUTS + o] = acc / tsumL[b] + bias[o];
    }
  }
}

// ---------------- launch ----------------
extern "C" void kernel_launch(void* const* d_in, const int* in_sizes, int n_in,
                              void* d_out, int out_size, void* d_ws, size_t ws_size,
                              hipStream_t stream) {
  const float* x    = (const float*)d_in[0];
  const float* th1  = (const float*)d_in[1];
  const float* th2  = (const float*)d_in[2];
  const float* mr   = (const float*)d_in[3];
  const float* mi   = (const float*)d_in[4];
  const float* wgt  = (const float*)d_in[5];
  const float* bias = (const float*)d_in[6];
  const int*   rows = (const int*)d_in[7];
  char* ws = (char*)d_ws;

  k_fused<<<NB*NSGQ*NTG, 256, 0, stream>>>(x, th1, th2, mr, mi, ws);
  k_reduce<<<dim3(NRBLK, NB), 256, 0, stream>>>(ws);
  k_tail<<<NSPLIT, 256, 0, stream>>>(wgt, bias, rows, ws, (float*)d_out);
}

// Round 3
// 137.739 us; speedup vs baseline: 1.2544x; 1.1957x over previous
//
#include <hip/hip_runtime.h>
#include <math.h>

// ---------------- problem constants ----------------
#define NB 8          // batch
#define NM 16         // modes
#define NPH 8         // photons
#define NSTATES 12870 // C(16,8)
#define NSUB 256      // 2^NPH column subsets
#define OUTS 128
#define NTILES 824    // sum over classes of ceil(R/4)*ceil(C/4)
#define NSLOTS (NTILES*16) // 13184
#define NSGQ 8        // s-groups of 32 (partial-accumulation granularity)
#define SPH 16        // s per LDS phase (2 phases per s-group)
#define NTG 4         // tile groups
#define TILES_PER_TG 206
#define SLOTS_PER_PG 128
#define NPGBLK 103    // 103*128 == NSLOTS

// ---------------- compile-time tables ----------------
struct Tables {
  int binom[17][9];
  unsigned char cls_masks[256]; // 8-bit masks sorted by (popcount, value)
  int cls_off[10];              // offsets into cls_masks per popcount
  int nt1[9], nt2[9];           // 4-tiles per dim per class
  int tile_off[10];
};

constexpr int cpopc(int x){ int c=0; while(x){ c += x & 1; x >>= 1; } return c; }

constexpr Tables make_tables(){
  Tables t{};
  for (int n=0;n<=16;n++)
    for (int k=0;k<=8;k++){
      if (k==0) t.binom[n][k]=1;
      else if (n==0) t.binom[n][k]=0;
      else t.binom[n][k]=t.binom[n-1][k-1]+t.binom[n-1][k];
    }
  int idx=0;
  for (int p=0;p<=8;p++){
    t.cls_off[p]=idx;
    for (int m=0;m<256;m++) if (cpopc(m)==p) t.cls_masks[idx++]=(unsigned char)m;
  }
  t.cls_off[9]=idx; // 256
  int toff=0;
  for (int c=0;c<=8;c++){
    int R=t.binom[8][c], C=t.binom[8][8-c];
    t.nt1[c]=(R+3)/4; t.nt2[c]=(C+3)/4;
    t.tile_off[c]=toff; toff += t.nt1[c]*t.nt2[c];
  }
  t.tile_off[9]=toff;
  return t;
}

constexpr Tables HTBL = make_tables();
static_assert(HTBL.tile_off[9]==NTILES, "tile count");
static_assert(HTBL.cls_off[9]==256, "mask count");
__device__ const Tables TBL = HTBL;

// next-pow2 shift for masks-per-level: C(8,p) = 1,8,28,56,70,56,28,8,1
__device__ const int LVL_SHIFT[9] = {0,3,5,6,7,6,5,3,0};

// ---------------- workspace layout (bytes) ----------------
#define WS_V      0                 // [NB][NSUB][NM] float2 = 262144
#define WS_TMAP   262144            // NSLOTS ints = 52736 (memset 0xFF)
#define WS_BSUM   315136            // [NPGBLK][NB] float = 3296
#define WS_POUT   319232            // [NPGBLK][NB][OUTS] float = 421888
#define WS_PART   741376            // [NB][NSGQ][NSLOTS] float2 = 6750208
#define TMAP_BYTES (NSLOTS*4)

// ---------------- complex helpers ----------------
__device__ __forceinline__ float2 cmul(float2 a, float2 b){
  return make_float2(fmaf(a.x,b.x,-(a.y*b.y)), fmaf(a.x,b.y, a.y*b.x));
}
__device__ __forceinline__ void cmac(float2& acc, float2 a, float2 b){
  acc.x = fmaf(a.x, b.x, acc.x); acc.x = fmaf(-a.y, b.y, acc.x);
  acc.y = fmaf(a.x, b.y, acc.y); acc.y = fmaf(a.y, b.x, acc.y);
}

// ---------------- K1: unitaries + V table + tile map ----------------
__global__ __launch_bounds__(256) void k_setup(
    const float* __restrict__ x, const float* __restrict__ th1,
    const float* __restrict__ th2, const float* __restrict__ mr,
    const float* __restrict__ mi, const int* __restrict__ rows, char* ws)
{
  int tid = threadIdx.x;
  if (blockIdx.x < NB) {
    int b = blockIdx.x;
    __shared__ float2 T1[NM][NM], T2[NM][NM], Am[NM][NM], Bm[NM][NM];
    __shared__ float2 EA[NM][NPH], Uin[NM][NPH], ex[NM];
    int r = tid >> 4, cc = tid & 15;
    {
      float sn, cs;
      sincosf(th1[r], &sn, &cs);
      float a = mr[0*256 + tid], bb = mi[0*256 + tid];   // M0[r][cc]
      T1[r][cc] = make_float2(cs*a - sn*bb, cs*bb + sn*a);
      sincosf(th2[r], &sn, &cs);
      float a2 = mr[2*256 + tid], b2 = mi[2*256 + tid];  // M2[r][cc]
      T2[r][cc] = make_float2(cs*a2 - sn*b2, cs*b2 + sn*a2);
    }
    __syncthreads();
    {
      float2 accA = make_float2(0,0), accB = make_float2(0,0);
      for (int m=0;m<NM;m++){
        float2 m1 = make_float2(mr[1*256 + r*16+m], mi[1*256 + r*16+m]);
        cmac(accA, m1, T1[m][cc]);
        float2 m3 = make_float2(mr[3*256 + r*16+m], mi[3*256 + r*16+m]);
        cmac(accB, m3, T2[m][cc]);
      }
      Am[r][cc] = accA; Bm[r][cc] = accB;
    }
    if (tid < NM){ float sn,cs; sincosf(x[b*NM+tid], &sn, &cs); ex[tid] = make_float2(cs, sn); }
    __syncthreads();
    if (tid < NM*NPH){ int m = tid >> 3, n = tid & 7; EA[m][n] = cmul(ex[m], Am[m][n]); }
    __syncthreads();
    if (tid < NM*NPH){
      int p = tid >> 3, n = tid & 7;
      float2 acc = make_float2(0,0);
      for (int m=0;m<NM;m++) cmac(acc, Bm[p][m], EA[m][n]);
      Uin[p][n] = acc;
    }
    __syncthreads();
    // V[s][m] = sum over set bits j of s of Uin[m][j];  thread tid == s
    float2* Vg = (float2*)(ws + WS_V);
    int s = tid;
    for (int m=0;m<NM;m++){
      float2 acc = make_float2(0,0);
      #pragma unroll
      for (int j=0;j<NPH;j++)
        if ((s>>j) & 1){ acc.x += Uin[m][j].x; acc.y += Uin[m][j].y; }
      Vg[b*(NSUB*NM) + s*NM + m] = acc;
    }
  } else {
    // tile map: state k -> (tile, slot)
    int k = (blockIdx.x - NB)*256 + tid;
    if (k < NSTATES){
      int t1=0, t2=0;
      #pragma unroll
      for (int i=0;i<NPH;i++){
        int rr = rows[k*NPH+i];
        if (rr < 8) t1 |= 1 << rr; else t2 |= 1 << (rr-8);
      }
      int c1 = __popc(t1);
      int rk1=0, cnt=0;
      #pragma unroll
      for (int bb=0;bb<8;bb++) if ((t1>>bb)&1){ cnt++; rk1 += TBL.binom[bb][cnt]; }
      int rk2=0; cnt=0;
      #pragma unroll
      for (int bb=0;bb<8;bb++) if ((t2>>bb)&1){ cnt++; rk2 += TBL.binom[bb][cnt]; }
      int tile = TBL.tile_off[c1] + (rk1>>2)*TBL.nt2[c1] + (rk2>>2);
      int slot = ((rk1&3)<<2) | (rk2&3);
      ((int*)(ws + WS_TMAP))[tile*16 + slot] = k;
    }
  }
}

// ---------------- K2: factorized Ryser main (round-0 verified structure) ---
__global__ __launch_bounds__(256) void k_main(char* ws)
{
  __shared__ float2 P1L[SPH][256];   // 32 KB
  __shared__ float2 P2L[SPH][256];   // 32 KB  (total exactly 64 KB)
  const float2* __restrict__ Vg = (const float2*)(ws + WS_V);
  float2* __restrict__ part = (float2*)(ws + WS_PART);
  int tid = threadIdx.x;
  int blk = blockIdx.x;
  int b = blk >> 5, rest = blk & 31, sgq = rest >> 2, tg = rest & 3;
  bool active = tid < TILES_PER_TG;
  int tile = tg + 4*tid;
  int t1v[4] = {0,0,0,0}, t2v[4] = {0,0,0,0};
  if (active){
    int c = 0;
    while (tile >= TBL.tile_off[c+1]) c++;
    int local = tile - TBL.tile_off[c];
    int n2 = TBL.nt2[c];
    int ti = local / n2, tj = local - ti*n2;
    int R = TBL.binom[8][c], C2 = TBL.binom[8][8-c];
    #pragma unroll
    for (int i=0;i<4;i++){ int r1 = ti*4+i; t1v[i] = (r1<R) ? (int)TBL.cls_masks[TBL.cls_off[c]+r1] : 0; }
    #pragma unroll
    for (int j=0;j<4;j++){ int r2 = tj*4+j; t2v[j] = (r2<C2) ? (int)TBL.cls_masks[TBL.cls_off[8-c]+r2] : 0; }
  }
  float2 acc[4][4] = {};
  for (int ph=0; ph<2; ph++){
    int sbase = sgq*32 + ph*SPH;
    // level-0 init (sign of Ryser folded into P1)
    if (tid < 2*SPH){
      int table = tid >> 4, s = tid & 15;
      float sg = 1.0f;
      if (table==0 && (__popc(sbase+s) & 1)) sg = -1.0f;
      (table ? P2L : P1L)[s][0] = make_float2(sg, 0.0f);
    }
    __syncthreads();
    // DP build: P[t] = P[t & (t-1)] * V[row(lowbit)]
    for (int p=1;p<=8;p++){
      int nm = TBL.cls_off[p+1]-TBL.cls_off[p];
      int sh = LVL_SHIFT[p];
      int tot = (2*SPH) << sh;
      for (int q=tid; q<tot; q+=256){
        int mi2 = q & ((1<<sh)-1);
        if (mi2 < nm){
          int ts = q >> sh; int s = ts & 15, table = ts >> 4;
          int t = (int)TBL.cls_masks[TBL.cls_off[p]+mi2];
          int par = t & (t-1);
          int row = (__ffs(t)-1) + table*8;
          float2 pv = (table ? P2L : P1L)[s][par];
          float2 vv = Vg[b*(NSUB*NM) + (sbase+s)*NM + row];
          (table ? P2L : P1L)[s][t] = cmul(pv, vv);
        }
      }
      __syncthreads();
    }
    // 4x4 register-tiled combine
    if (active){
      for (int s=0;s<SPH;s++){
        float2 av[4], bv[4];
        #pragma unroll
        for (int i=0;i<4;i++) av[i] = P1L[s][t1v[i]];
        #pragma unroll
        for (int j=0;j<4;j++) bv[j] = P2L[s][t2v[j]];
        #pragma unroll
        for (int i=0;i<4;i++)
          #pragma unroll
          for (int j=0;j<4;j++) cmac(acc[i][j], av[i], bv[j]);
      }
    }
    __syncthreads();
  }
  if (active){
    float2* dst = part + (size_t)(b*NSGQ + sgq)*NSLOTS + (size_t)tile*16;
    #pragma unroll
    for (int i=0;i<4;i++)
      #pragma unroll
      for (int j=0;j<4;j++) dst[i*4+j] = acc[i][j];
  }
}

// ---------------- K3: slot-driven reduce + gemm partials ----------------
// grid NPGBLK(103) x 256. Block owns 128 consecutive slots.
// (A) krow[sl] = tmap[slot]  (pad -> -1)
// (B) coalesced reduce of part over 8 s-groups -> prob[b][sl] in LDS (pads -> 0)
// (C) per-b norm partials -> bsum
// (D) row-driven gemm: per slot one 512B weight row, shared across 8 b
// (E) write pout[blk][b][o]
__global__ __launch_bounds__(256) void k_pg(
    const float* __restrict__ wgt, char* ws)
{
  __shared__ float prob[NB][SLOTS_PER_PG];   // 4 KB
  __shared__ int   krow[SLOTS_PER_PG];       // 0.5 KB
  __shared__ float hacc[2][NB][OUTS];        // 8 KB
  int tid = threadIdx.x;
  int blk = blockIdx.x;
  int slot0 = blk * SLOTS_PER_PG;

  if (tid < SLOTS_PER_PG)
    krow[tid] = ((const int*)(ws + WS_TMAP))[slot0 + tid];
  __syncthreads();

  // (B) coalesced partial reduce
  const float2* __restrict__ part = (const float2*)(ws + WS_PART);
  for (int idx = tid; idx < NB*SLOTS_PER_PG; idx += 256){
    int b = idx >> 7, sl = idx & 127;
    float2 amp = make_float2(0,0);
    #pragma unroll
    for (int g=0; g<NSGQ; g++){
      float2 v = part[(size_t)(b*NSGQ + g)*NSLOTS + slot0 + sl];
      amp.x += v.x; amp.y += v.y;
    }
    prob[b][sl] = (krow[sl] >= 0) ? fmaf(amp.x, amp.x, amp.y*amp.y) : 0.0f;
  }
  __syncthreads();

  // (C) per-b norm partial sums
  float* bsum = (float*)(ws + WS_BSUM);
  {
    int b = tid >> 5, l = tid & 31;
    float v = 0.0f;
    #pragma unroll
    for (int sl = 0; sl < SLOTS_PER_PG; sl += 32) v += prob[b][sl + l];
    #pragma unroll
    for (int off=16; off>0; off>>=1) v += __shfl_down(v, off, 32);
    if (l == 0) bsum[blk*NB + b] = v;
  }

  // (D) row-driven gemm: half owns 64 slots, thread owns column o
  {
    int half = tid >> 7, o = tid & 127;
    float acc[NB] = {0,0,0,0,0,0,0,0};
    int sbeg = half*64, send = sbeg + 64;
    #pragma unroll 4
    for (int sl = sbeg; sl < send; sl++){
      int kr = krow[sl]; if (kr < 0) kr = 0;   // prob already 0 for pads
      float wv = wgt[(size_t)kr * OUTS + o];
      #pragma unroll
      for (int b=0;b<NB;b++) acc[b] = fmaf(prob[b][sl], wv, acc[b]);
    }
    #pragma unroll
    for (int b=0;b<NB;b++) hacc[half][b][o] = acc[b];
  }
  __syncthreads();

  // (E) combine halves -> pout
  float* pout = (float*)(ws + WS_POUT);
  for (int idx = tid; idx < NB*OUTS; idx += 256){
    int b = idx >> 7, o = idx & 127;
    pout[(size_t)blk*(NB*OUTS) + idx] = hacc[0][b][o] + hacc[1][b][o];
  }
}

// ---------------- K4: final reduce: out = (sum pout)/(sum bsum) + bias ----
// grid NB x 128 threads.
__global__ __launch_bounds__(128) void k_final(
    const float* __restrict__ bias, const char* __restrict__ ws,
    float* __restrict__ out)
{
  const float* __restrict__ pout = (const float*)(ws + WS_POUT);
  const float* __restrict__ bsum = (const float*)(ws + WS_BSUM);
  int o = threadIdx.x, b = blockIdx.x;
  float sum = 0.0f;
  #pragma unroll 4
  for (int j=0;j<NPGBLK;j++) sum += bsum[j*NB + b];
  float acc = 0.0f;
  #pragma unroll 8
  for (int s=0;s<NPGBLK;s++) acc += pout[(size_t)s*(NB*OUTS) + b*OUTS + o];
  out[b*OUTS + o] = acc / sum + bias[o];
}

// ---------------- launch ----------------
extern "C" void kernel_launch(void* const* d_in, const int* in_sizes, int n_in,
                              void* d_out, int out_size, void* d_ws, size_t ws_size,
                              hipStream_t stream) {
  const float* x    = (const float*)d_in[0];
  const float* th1  = (const float*)d_in[1];
  const float* th2  = (const float*)d_in[2];
  const float* mr   = (const float*)d_in[3];
  const float* mi   = (const float*)d_in[4];
  const float* wgt  = (const float*)d_in[5];
  const float* bias = (const float*)d_in[6];
  const int*   rows = (const int*)d_in[7];
  float* out = (float*)d_out;
  char* ws = (char*)d_ws;

  hipMemsetAsync(ws + WS_TMAP, 0xFF, TMAP_BYTES, stream);
  k_setup<<<NB + (NSTATES + 255)/256, 256, 0, stream>>>(x, th1, th2, mr, mi, rows, ws);
  k_main<<<NB*NSGQ*NTG, 256, 0, stream>>>(ws);
  k_pg<<<NPGBLK, 256, 0, stream>>>(wgt, ws);
  k_final<<<NB, 128, 0, stream>>>(bias, ws, out);
}

// Round 4
// 134.197 us; speedup vs baseline: 1.2875x; 1.0264x over previous
//
#include <hip/hip_runtime.h>
#include <math.h>

// ---------------- problem constants ----------------
#define NB 8          // batch
#define NM 16         // modes
#define NPH 8         // photons
#define NSTATES 12870 // C(16,8)
#define NSUB 256      // 2^NPH column subsets
#define OUTS 128
#define NTILES 824    // sum over classes of ceil(R/4)*ceil(C/4)
#define NSLOTS (NTILES*16) // 13184
#define NSG 16        // s-groups of 16 (partial-accumulation granularity)
#define SPH 16        // s per k_main block (one phase per block)
#define NTG 4         // tile groups
#define TILES_PER_TG 206
#define SLOTS_PER_PG 64
#define NPGBLK 206    // 206*64 == NSLOTS

// ---------------- compile-time tables ----------------
struct Tables {
  int binom[17][9];
  unsigned char cls_masks[256]; // 8-bit masks sorted by (popcount, value)
  int cls_off[10];              // offsets into cls_masks per popcount
  int nt1[9], nt2[9];           // 4-tiles per dim per class
  int tile_off[10];
};

constexpr int cpopc(int x){ int c=0; while(x){ c += x & 1; x >>= 1; } return c; }

constexpr Tables make_tables(){
  Tables t{};
  for (int n=0;n<=16;n++)
    for (int k=0;k<=8;k++){
      if (k==0) t.binom[n][k]=1;
      else if (n==0) t.binom[n][k]=0;
      else t.binom[n][k]=t.binom[n-1][k-1]+t.binom[n-1][k];
    }
  int idx=0;
  for (int p=0;p<=8;p++){
    t.cls_off[p]=idx;
    for (int m=0;m<256;m++) if (cpopc(m)==p) t.cls_masks[idx++]=(unsigned char)m;
  }
  t.cls_off[9]=idx; // 256
  int toff=0;
  for (int c=0;c<=8;c++){
    int R=t.binom[8][c], C=t.binom[8][8-c];
    t.nt1[c]=(R+3)/4; t.nt2[c]=(C+3)/4;
    t.tile_off[c]=toff; toff += t.nt1[c]*t.nt2[c];
  }
  t.tile_off[9]=toff;
  return t;
}

constexpr Tables HTBL = make_tables();
static_assert(HTBL.tile_off[9]==NTILES, "tile count");
static_assert(HTBL.cls_off[9]==256, "mask count");
__device__ const Tables TBL = HTBL;

// next-pow2 shift for masks-per-level: C(8,p) = 1,8,28,56,70,56,28,8,1
__device__ const int LVL_SHIFT[9] = {0,3,5,6,7,6,5,3,0};

// ---------------- workspace layout (bytes) ----------------
#define WS_V      0                 // [NB][NSUB][NM] float2 = 262144
#define WS_TMAP   262144            // NSLOTS ints = 52736 (memset 0xFF) -> 314880
#define WS_BSUM   315136            // [NPGBLK][NB] float = 6592 -> 321728
#define WS_POUT   322560            // [NPGBLK][NB][OUTS] float = 843776 -> 1166336
#define WS_PART   1179648           // [NB][NSG][NSLOTS] float2 = 13500416
#define TMAP_BYTES (NSLOTS*4)

// ---------------- complex helpers ----------------
__device__ __forceinline__ float2 cmul(float2 a, float2 b){
  return make_float2(fmaf(a.x,b.x,-(a.y*b.y)), fmaf(a.x,b.y, a.y*b.x));
}
__device__ __forceinline__ void cmac(float2& acc, float2 a, float2 b){
  acc.x = fmaf(a.x, b.x, acc.x); acc.x = fmaf(-a.y, b.y, acc.x);
  acc.y = fmaf(a.x, b.y, acc.y); acc.y = fmaf(a.y, b.x, acc.y);
}

// ---------------- K1: unitaries + V table + tile map ----------------
__global__ __launch_bounds__(256) void k_setup(
    const float* __restrict__ x, const float* __restrict__ th1,
    const float* __restrict__ th2, const float* __restrict__ mr,
    const float* __restrict__ mi, const int* __restrict__ rows, char* ws)
{
  int tid = threadIdx.x;
  if (blockIdx.x < NB) {
    int b = blockIdx.x;
    __shared__ float2 T1[NM][NM], T2[NM][NM], Am[NM][NM], Bm[NM][NM];
    __shared__ float2 EA[NM][NPH], Uin[NM][NPH], ex[NM];
    int r = tid >> 4, cc = tid & 15;
    {
      float sn, cs;
      sincosf(th1[r], &sn, &cs);
      float a = mr[0*256 + tid], bb = mi[0*256 + tid];   // M0[r][cc]
      T1[r][cc] = make_float2(cs*a - sn*bb, cs*bb + sn*a);
      sincosf(th2[r], &sn, &cs);
      float a2 = mr[2*256 + tid], b2 = mi[2*256 + tid];  // M2[r][cc]
      T2[r][cc] = make_float2(cs*a2 - sn*b2, cs*b2 + sn*a2);
    }
    __syncthreads();
    {
      float2 accA = make_float2(0,0), accB = make_float2(0,0);
      for (int m=0;m<NM;m++){
        float2 m1 = make_float2(mr[1*256 + r*16+m], mi[1*256 + r*16+m]);
        cmac(accA, m1, T1[m][cc]);
        float2 m3 = make_float2(mr[3*256 + r*16+m], mi[3*256 + r*16+m]);
        cmac(accB, m3, T2[m][cc]);
      }
      Am[r][cc] = accA; Bm[r][cc] = accB;
    }
    if (tid < NM){ float sn,cs; sincosf(x[b*NM+tid], &sn, &cs); ex[tid] = make_float2(cs, sn); }
    __syncthreads();
    if (tid < NM*NPH){ int m = tid >> 3, n = tid & 7; EA[m][n] = cmul(ex[m], Am[m][n]); }
    __syncthreads();
    if (tid < NM*NPH){
      int p = tid >> 3, n = tid & 7;
      float2 acc = make_float2(0,0);
      for (int m=0;m<NM;m++) cmac(acc, Bm[p][m], EA[m][n]);
      Uin[p][n] = acc;
    }
    __syncthreads();
    // V[s][m] = sum over set bits j of s of Uin[m][j];  thread tid == s
    float2* Vg = (float2*)(ws + WS_V);
    int s = tid;
    for (int m=0;m<NM;m++){
      float2 acc = make_float2(0,0);
      #pragma unroll
      for (int j=0;j<NPH;j++)
        if ((s>>j) & 1){ acc.x += Uin[m][j].x; acc.y += Uin[m][j].y; }
      Vg[b*(NSUB*NM) + s*NM + m] = acc;
    }
  } else {
    // tile map: state k -> (tile, slot)
    int k = (blockIdx.x - NB)*256 + tid;
    if (k < NSTATES){
      int t1=0, t2=0;
      #pragma unroll
      for (int i=0;i<NPH;i++){
        int rr = rows[k*NPH+i];
        if (rr < 8) t1 |= 1 << rr; else t2 |= 1 << (rr-8);
      }
      int c1 = __popc(t1);
      int rk1=0, cnt=0;
      #pragma unroll
      for (int bb=0;bb<8;bb++) if ((t1>>bb)&1){ cnt++; rk1 += TBL.binom[bb][cnt]; }
      int rk2=0; cnt=0;
      #pragma unroll
      for (int bb=0;bb<8;bb++) if ((t2>>bb)&1){ cnt++; rk2 += TBL.binom[bb][cnt]; }
      int tile = TBL.tile_off[c1] + (rk1>>2)*TBL.nt2[c1] + (rk2>>2);
      int slot = ((rk1&3)<<2) | (rk2&3);
      ((int*)(ws + WS_TMAP))[tile*16 + slot] = k;
    }
  }
}

// ---------------- K2: factorized Ryser main, one 16-s phase per block ------
// grid 512 = NB(8) x NSG(16) x NTG(4); 64 KB LDS, 256 thr -> 2 blocks/CU.
// During one block's DP barriers the co-resident block's waves execute.
__global__ __launch_bounds__(256) void k_main(char* ws)
{
  __shared__ float2 P1L[SPH][256];   // 32 KB
  __shared__ float2 P2L[SPH][256];   // 32 KB  (total exactly 64 KB)
  const float2* __restrict__ Vg = (const float2*)(ws + WS_V);
  float2* __restrict__ part = (float2*)(ws + WS_PART);
  int tid = threadIdx.x;
  int blk = blockIdx.x;
  int b = blk >> 6, rest = blk & 63, sg = rest >> 2, tg = rest & 3;
  int sbase = sg * SPH;
  bool active = tid < TILES_PER_TG;
  int tile = tg + 4*tid;
  int t1v[4] = {0,0,0,0}, t2v[4] = {0,0,0,0};
  if (active){
    int c = 0;
    while (tile >= TBL.tile_off[c+1]) c++;
    int local = tile - TBL.tile_off[c];
    int n2 = TBL.nt2[c];
    int ti = local / n2, tj = local - ti*n2;
    int R = TBL.binom[8][c], C2 = TBL.binom[8][8-c];
    #pragma unroll
    for (int i=0;i<4;i++){ int r1 = ti*4+i; t1v[i] = (r1<R) ? (int)TBL.cls_masks[TBL.cls_off[c]+r1] : 0; }
    #pragma unroll
    for (int j=0;j<4;j++){ int r2 = tj*4+j; t2v[j] = (r2<C2) ? (int)TBL.cls_masks[TBL.cls_off[8-c]+r2] : 0; }
  }
  // level-0 init (sign of Ryser folded into P1)
  if (tid < 2*SPH){
    int table = tid >> 4, s = tid & 15;
    float sgn = 1.0f;
    if (table==0 && (__popc(sbase+s) & 1)) sgn = -1.0f;
    (table ? P2L : P1L)[s][0] = make_float2(sgn, 0.0f);
  }
  __syncthreads();
  // DP build: P[t] = P[t & (t-1)] * V[row(lowbit)]
  for (int p=1;p<=8;p++){
    int nm = TBL.cls_off[p+1]-TBL.cls_off[p];
    int sh = LVL_SHIFT[p];
    int tot = (2*SPH) << sh;
    for (int q=tid; q<tot; q+=256){
      int mi2 = q & ((1<<sh)-1);
      if (mi2 < nm){
        int ts = q >> sh; int s = ts & 15, table = ts >> 4;
        int t = (int)TBL.cls_masks[TBL.cls_off[p]+mi2];
        int par = t & (t-1);
        int row = (__ffs(t)-1) + table*8;
        float2 pv = (table ? P2L : P1L)[s][par];
        float2 vv = Vg[b*(NSUB*NM) + (sbase+s)*NM + row];
        (table ? P2L : P1L)[s][t] = cmul(pv, vv);
      }
    }
    __syncthreads();
  }
  // 4x4 register-tiled combine over this block's 16 s
  if (active){
    float2 acc[4][4] = {};
    for (int s=0;s<SPH;s++){
      float2 av[4], bv[4];
      #pragma unroll
      for (int i=0;i<4;i++) av[i] = P1L[s][t1v[i]];
      #pragma unroll
      for (int j=0;j<4;j++) bv[j] = P2L[s][t2v[j]];
      #pragma unroll
      for (int i=0;i<4;i++)
        #pragma unroll
        for (int j=0;j<4;j++) cmac(acc[i][j], av[i], bv[j]);
    }
    float2* dst = part + (size_t)(b*NSG + sg)*NSLOTS + (size_t)tile*16;
    #pragma unroll
    for (int i=0;i<4;i++)
      #pragma unroll
      for (int j=0;j<4;j++) dst[i*4+j] = acc[i][j];
  }
}

// ---------------- K3: slot-driven reduce + gemm partials ----------------
// grid NPGBLK(206) x 512 threads. Block owns 64 consecutive slots.
// (A) krow from tmap; (B) coalesced reduce over 16 s-groups -> prob LDS;
// (C) per-b norm partials (one wave per b); (D) gemm split 4-way over
// slot-quarters; (E) hacc combine -> pout.
__global__ __launch_bounds__(512) void k_pg(
    const float* __restrict__ wgt, char* ws)
{
  __shared__ float prob[NB][SLOTS_PER_PG];   // 2 KB
  __shared__ int   krow[SLOTS_PER_PG];       // 256 B
  __shared__ float hacc[4][NB][OUTS];        // 16 KB
  int tid = threadIdx.x;
  int blk = blockIdx.x;
  int slot0 = blk * SLOTS_PER_PG;

  if (tid < SLOTS_PER_PG)
    krow[tid] = ((const int*)(ws + WS_TMAP))[slot0 + tid];
  __syncthreads();

  // (B) coalesced partial reduce: one (b, sl) per thread
  const float2* __restrict__ part = (const float2*)(ws + WS_PART);
  {
    int b = tid >> 6, sl = tid & 63;
    float2 amp = make_float2(0,0);
    #pragma unroll
    for (int g=0; g<NSG; g++){
      float2 v = part[(size_t)(b*NSG + g)*NSLOTS + slot0 + sl];
      amp.x += v.x; amp.y += v.y;
    }
    prob[b][sl] = (krow[sl] >= 0) ? fmaf(amp.x, amp.x, amp.y*amp.y) : 0.0f;
  }
  __syncthreads();

  // (C) per-b norm partial sums: thread group (b = wave) of 64 lanes
  float* bsum = (float*)(ws + WS_BSUM);
  {
    int b = tid >> 6, l = tid & 63;
    float v = prob[b][l];
    #pragma unroll
    for (int off=32; off>0; off>>=1) v += __shfl_down(v, off);
    if (l == 0) bsum[blk*NB + b] = v;
  }

  // (D) gemm: quarter q owns 16 slots, thread owns column o
  {
    int q = tid >> 7, o = tid & 127;
    float acc[NB] = {0,0,0,0,0,0,0,0};
    int sbeg = q*16, send = sbeg + 16;
    #pragma unroll 4
    for (int sl = sbeg; sl < send; sl++){
      int kr = krow[sl]; if (kr < 0) kr = 0;   // prob already 0 for pads
      float wv = wgt[(size_t)kr * OUTS + o];
      #pragma unroll
      for (int b=0;b<NB;b++) acc[b] = fmaf(prob[b][sl], wv, acc[b]);
    }
    #pragma unroll
    for (int b=0;b<NB;b++) hacc[q][b][o] = acc[b];
  }
  __syncthreads();

  // (E) combine quarters -> pout
  float* pout = (float*)(ws + WS_POUT);
  for (int idx = tid; idx < NB*OUTS; idx += 512){
    float s = hacc[0][0][idx] + hacc[1][0][idx] + hacc[2][0][idx] + hacc[3][0][idx];
    pout[(size_t)blk*(NB*OUTS) + idx] = s;
  }
}

// ---------------- K4: final reduce: out = (sum pout)/(sum bsum) + bias ----
// grid NB x 256 threads.
__global__ __launch_bounds__(256) void k_final(
    const float* __restrict__ bias, const char* __restrict__ ws,
    float* __restrict__ out)
{
  const float* __restrict__ pout = (const float*)(ws + WS_POUT);
  const float* __restrict__ bsum = (const float*)(ws + WS_BSUM);
  __shared__ float accs[2][OUTS];
  __shared__ float wred[4];
  int tid = threadIdx.x, b = blockIdx.x;
  // norm: block-reduce of 206 bsum entries
  float v = 0.0f;
  for (int j = tid; j < NPGBLK; j += 256) v += bsum[j*NB + b];
  #pragma unroll
  for (int off=32; off>0; off>>=1) v += __shfl_down(v, off);
  if ((tid & 63) == 0) wred[tid >> 6] = v;
  // pout halves
  int o = tid & 127, half = tid >> 7;
  float a = 0.0f;
  for (int s = half; s < NPGBLK; s += 2) a += pout[(size_t)s*(NB*OUTS) + b*OUTS + o];
  accs[half][o] = a;
  __syncthreads();
  if (tid < OUTS){
    float sum = wred[0] + wred[1] + wred[2] + wred[3];
    out[b*OUTS + tid] = (accs[0][tid] + accs[1][tid]) / sum + bias[tid];
  }
}

// ---------------- launch ----------------
extern "C" void kernel_launch(void* const* d_in, const int* in_sizes, int n_in,
                              void* d_out, int out_size, void* d_ws, size_t ws_size,
                              hipStream_t stream) {
  const float* x    = (const float*)d_in[0];
  const float* th1  = (const float*)d_in[1];
  const float* th2  = (const float*)d_in[2];
  const float* mr   = (const float*)d_in[3];
  const float* mi   = (const float*)d_in[4];
  const float* wgt  = (const float*)d_in[5];
  const float* bias = (const float*)d_in[6];
  const int*   rows = (const int*)d_in[7];
  float* out = (float*)d_out;
  char* ws = (char*)d_ws;

  hipMemsetAsync(ws + WS_TMAP, 0xFF, TMAP_BYTES, stream);
  k_setup<<<NB + (NSTATES + 255)/256, 256, 0, stream>>>(x, th1, th2, mr, mi, rows, ws);
  k_main<<<NB*NSG*NTG, 256, 0, stream>>>(ws);
  k_pg<<<NPGBLK, 512, 0, stream>>>(wgt, ws);
  k_final<<<NB, 256, 0, stream>>>(bias, ws, out);
}

// Round 5
// 126.677 us; speedup vs baseline: 1.3639x; 1.0594x over previous
//
#include <hip/hip_runtime.h>
#include <math.h>

// ---------------- problem constants ----------------
#define NB 8          // batch
#define NM 16         // modes
#define NPH 8         // photons
#define NSTATES 12870 // C(16,8)
#define NSUB 256      // 2^NPH column subsets
#define OUTS 128
#define NTILES 824    // sum over classes of ceil(R/4)*ceil(C/4)
#define NSLOTS (NTILES*16) // 13184
#define NSG 16        // s-groups of 16 (partial-accumulation granularity)
#define SPH 16        // s per k_main block
#define NTG 4         // tile groups
#define TILES_PER_TG 206
#define SLOTS_PER_PG 64
#define NPGBLK 206    // 206*64 == NSLOTS

// ---------------- compile-time tables ----------------
struct Tables {
  int binom[17][9];
  unsigned char cls_masks[256]; // 8-bit masks sorted by (popcount, value)
  int cls_off[10];              // offsets into cls_masks per popcount
  int nt1[9], nt2[9];           // 4-tiles per dim per class
  int tile_off[10];
};

constexpr int cpopc(int x){ int c=0; while(x){ c += x & 1; x >>= 1; } return c; }

constexpr Tables make_tables(){
  Tables t{};
  for (int n=0;n<=16;n++)
    for (int k=0;k<=8;k++){
      if (k==0) t.binom[n][k]=1;
      else if (n==0) t.binom[n][k]=0;
      else t.binom[n][k]=t.binom[n-1][k-1]+t.binom[n-1][k];
    }
  int idx=0;
  for (int p=0;p<=8;p++){
    t.cls_off[p]=idx;
    for (int m=0;m<256;m++) if (cpopc(m)==p) t.cls_masks[idx++]=(unsigned char)m;
  }
  t.cls_off[9]=idx; // 256
  int toff=0;
  for (int c=0;c<=8;c++){
    int R=t.binom[8][c], C=t.binom[8][8-c];
    t.nt1[c]=(R+3)/4; t.nt2[c]=(C+3)/4;
    t.tile_off[c]=toff; toff += t.nt1[c]*t.nt2[c];
  }
  t.tile_off[9]=toff;
  return t;
}

constexpr Tables HTBL = make_tables();
static_assert(HTBL.tile_off[9]==NTILES, "tile count");
static_assert(HTBL.cls_off[9]==256, "mask count");
__device__ const Tables TBL = HTBL;

// ---------------- workspace layout (bytes) ----------------
#define WS_V      0                 // [NB][NSUB][NM] float2 = 262144
#define WS_TMAP   262144            // NSLOTS ints = 52736 -> 314880 (no memset; pads detected analytically)
#define WS_BSUM   315136            // [NPGBLK][NB] float = 6592 -> 321728
#define WS_POUT   322560            // [NPGBLK][NB][OUTS] float = 843776 -> 1166336
#define WS_PART   1179648           // [NB][NSG][NSLOTS] float2 = 13500416

// ---------------- complex helpers ----------------
__device__ __forceinline__ float2 cmul(float2 a, float2 b){
  return make_float2(fmaf(a.x,b.x,-(a.y*b.y)), fmaf(a.x,b.y, a.y*b.x));
}
__device__ __forceinline__ void cmac(float2& acc, float2 a, float2 b){
  acc.x = fmaf(a.x, b.x, acc.x); acc.x = fmaf(-a.y, b.y, acc.x);
  acc.y = fmaf(a.x, b.y, acc.y); acc.y = fmaf(a.y, b.x, acc.y);
}

// ---------------- K1: unitaries + V table + tile map ----------------
__global__ __launch_bounds__(256) void k_setup(
    const float* __restrict__ x, const float* __restrict__ th1,
    const float* __restrict__ th2, const float* __restrict__ mr,
    const float* __restrict__ mi, const int* __restrict__ rows, char* ws)
{
  int tid = threadIdx.x;
  if (blockIdx.x < NB) {
    int b = blockIdx.x;
    __shared__ float2 T1[NM][NM], T2[NM][NM], Am[NM][NM], Bm[NM][NM];
    __shared__ float2 EA[NM][NPH], Uin[NM][NPH], ex[NM];
    int r = tid >> 4, cc = tid & 15;
    {
      float sn, cs;
      sincosf(th1[r], &sn, &cs);
      float a = mr[0*256 + tid], bb = mi[0*256 + tid];   // M0[r][cc]
      T1[r][cc] = make_float2(cs*a - sn*bb, cs*bb + sn*a);
      sincosf(th2[r], &sn, &cs);
      float a2 = mr[2*256 + tid], b2 = mi[2*256 + tid];  // M2[r][cc]
      T2[r][cc] = make_float2(cs*a2 - sn*b2, cs*b2 + sn*a2);
    }
    __syncthreads();
    {
      float2 accA = make_float2(0,0), accB = make_float2(0,0);
      for (int m=0;m<NM;m++){
        float2 m1 = make_float2(mr[1*256 + r*16+m], mi[1*256 + r*16+m]);
        cmac(accA, m1, T1[m][cc]);
        float2 m3 = make_float2(mr[3*256 + r*16+m], mi[3*256 + r*16+m]);
        cmac(accB, m3, T2[m][cc]);
      }
      Am[r][cc] = accA; Bm[r][cc] = accB;
    }
    if (tid < NM){ float sn,cs; sincosf(x[b*NM+tid], &sn, &cs); ex[tid] = make_float2(cs, sn); }
    __syncthreads();
    if (tid < NM*NPH){ int m = tid >> 3, n = tid & 7; EA[m][n] = cmul(ex[m], Am[m][n]); }
    __syncthreads();
    if (tid < NM*NPH){
      int p = tid >> 3, n = tid & 7;
      float2 acc = make_float2(0,0);
      for (int m=0;m<NM;m++) cmac(acc, Bm[p][m], EA[m][n]);
      Uin[p][n] = acc;
    }
    __syncthreads();
    // V[s][m] = sum over set bits j of s of Uin[m][j];  thread tid == s
    float2* Vg = (float2*)(ws + WS_V);
    int s = tid;
    for (int m=0;m<NM;m++){
      float2 acc = make_float2(0,0);
      #pragma unroll
      for (int j=0;j<NPH;j++)
        if ((s>>j) & 1){ acc.x += Uin[m][j].x; acc.y += Uin[m][j].y; }
      Vg[b*(NSUB*NM) + s*NM + m] = acc;
    }
  } else {
    // tile map: state k -> (tile, slot)
    int k = (blockIdx.x - NB)*256 + tid;
    if (k < NSTATES){
      int t1=0, t2=0;
      #pragma unroll
      for (int i=0;i<NPH;i++){
        int rr = rows[k*NPH+i];
        if (rr < 8) t1 |= 1 << rr; else t2 |= 1 << (rr-8);
      }
      int c1 = __popc(t1);
      int rk1=0, cnt=0;
      #pragma unroll
      for (int bb=0;bb<8;bb++) if ((t1>>bb)&1){ cnt++; rk1 += TBL.binom[bb][cnt]; }
      int rk2=0; cnt=0;
      #pragma unroll
      for (int bb=0;bb<8;bb++) if ((t2>>bb)&1){ cnt++; rk2 += TBL.binom[bb][cnt]; }
      int tile = TBL.tile_off[c1] + (rk1>>2)*TBL.nt2[c1] + (rk2>>2);
      int slot = ((rk1&3)<<2) | (rk2&3);
      ((int*)(ws + WS_TMAP))[tile*16 + slot] = k;
    }
  }
}

// ---------------- K2: barrier-free direct-product fill + combine ----------
// grid 512 = NB(8) x NSG(16) x NTG(4); 64 KB LDS, 256 thr -> 2 blocks/CU.
// Each thread owns (table, s, 32-t chunk): loads its 8 V values to registers,
// builds all 32 subset products with a fully unrolled in-register DP
// (bit-identical multiply order to the old LDS DP), writes once to LDS with
// an XOR bank swizzle. ONE barrier, then the 4x4 register-tiled combine.
__global__ __launch_bounds__(256) void k_main(char* ws)
{
  __shared__ float2 P[32][256];      // 64 KB; row ts = table*16+s, col swizzled
  const float2* __restrict__ Vg = (const float2*)(ws + WS_V);
  float2* __restrict__ part = (float2*)(ws + WS_PART);
  int tid = threadIdx.x;
  int blk = blockIdx.x;
  int b = blk >> 6, rest = blk & 63, sg = rest >> 2, tg = rest & 3;
  int sbase = sg * SPH;

  // ---- fill: thread -> (ts = table*16+s, chunk of 32 t-values) ----
  {
    int ts = tid >> 3;               // 0..31
    int table = ts >> 4, sl = ts & 15;
    int chunk = tid & 7;
    int t0 = chunk << 5;
    float2 v[8];
    const float2* vrow = Vg + (size_t)b*(NSUB*NM) + (size_t)(sbase+sl)*NM + table*8;
    #pragma unroll
    for (int j=0;j<8;j++) v[j] = vrow[j];
    // high bits (t bits 5..7 = chunk bits 0..2), order v7,v6,v5 = old chain order
    float2 ph = make_float2((table==0 && (__popc(sbase+sl)&1)) ? -1.0f : 1.0f, 0.0f);
    if (chunk & 4) ph = cmul(ph, v[7]);
    if (chunk & 2) ph = cmul(ph, v[6]);
    if (chunk & 1) ph = cmul(ph, v[5]);
    float2 p[32];
    p[0] = ph;
    #pragma unroll
    for (int u=1; u<32; u++){
      int par = u & (u-1);
      int lb = (u&1) ? 0 : ((u&2) ? 1 : ((u&4) ? 2 : ((u&8) ? 3 : 4)));
      p[u] = cmul(p[par], v[lb]);
    }
    int swz = (ts & 15) << 1;        // XOR on t bits 1..4 (bit0 preserved)
    #pragma unroll
    for (int u=0; u<32; u+=2){
      int tc = (t0 + u) ^ swz;
      *(float4*)&P[ts][tc] = make_float4(p[u].x, p[u].y, p[u+1].x, p[u+1].y);
    }
  }

  // combine-thread tile masks (registers + const tables only)
  bool active = tid < TILES_PER_TG;
  int tile = tg + 4*tid;
  int t1v[4] = {0,0,0,0}, t2v[4] = {0,0,0,0};
  if (active){
    int c = 0;
    while (tile >= TBL.tile_off[c+1]) c++;
    int local = tile - TBL.tile_off[c];
    int n2 = TBL.nt2[c];
    int ti = local / n2, tj = local - ti*n2;
    int R = TBL.binom[8][c], C2 = TBL.binom[8][8-c];
    #pragma unroll
    for (int i=0;i<4;i++){ int r1 = ti*4+i; t1v[i] = (r1<R) ? (int)TBL.cls_masks[TBL.cls_off[c]+r1] : 0; }
    #pragma unroll
    for (int j=0;j<4;j++){ int r2 = tj*4+j; t2v[j] = (r2<C2) ? (int)TBL.cls_masks[TBL.cls_off[8-c]+r2] : 0; }
  }
  __syncthreads();   // the ONE barrier: P table ready

  // ---- 4x4 register-tiled combine over this block's 16 s ----
  if (active){
    float2 acc[4][4] = {};
    for (int s=0;s<SPH;s++){
      int swz = s << 1;
      float2 av[4], bv[4];
      #pragma unroll
      for (int i=0;i<4;i++) av[i] = P[s][t1v[i] ^ swz];
      #pragma unroll
      for (int j=0;j<4;j++) bv[j] = P[16+s][t2v[j] ^ swz];
      #pragma unroll
      for (int i=0;i<4;i++)
        #pragma unroll
        for (int j=0;j<4;j++) cmac(acc[i][j], av[i], bv[j]);
    }
    float2* dst = part + (size_t)(b*NSG + sg)*NSLOTS + (size_t)tile*16;
    #pragma unroll
    for (int i=0;i<4;i++)
      #pragma unroll
      for (int j=0;j<4;j++) dst[i*4+j] = acc[i][j];
  }
}

// ---------------- K3: slot-driven reduce + gemm partials ----------------
// grid NPGBLK(206) x 512 threads. Block owns 64 consecutive slots.
// Pad slots detected ANALYTICALLY (no tmap memset needed); tmap read only
// at valid slots, which k_setup always writes.
__global__ __launch_bounds__(512) void k_pg(
    const float* __restrict__ wgt, char* ws)
{
  __shared__ float prob[NB][SLOTS_PER_PG];   // 2 KB
  __shared__ int   krow[SLOTS_PER_PG];       // 256 B
  __shared__ float hacc[4][NB][OUTS];        // 16 KB
  int tid = threadIdx.x;
  int blk = blockIdx.x;
  int slot0 = blk * SLOTS_PER_PG;

  if (tid < SLOTS_PER_PG){
    int slot = slot0 + tid;
    int tile = slot >> 4;
    int c = 0;
    while (tile >= TBL.tile_off[c+1]) c++;
    int local = tile - TBL.tile_off[c];
    int n2 = TBL.nt2[c];
    int ti = local / n2, tj = local - ti*n2;
    int r1 = ti*4 + ((tid >> 2) & 3);
    int r2 = tj*4 + (tid & 3);
    bool pad = (r1 >= TBL.binom[8][c]) || (r2 >= TBL.binom[8][8-c]);
    krow[tid] = pad ? -1 : ((const int*)(ws + WS_TMAP))[slot];
  }
  __syncthreads();

  // (B) coalesced partial reduce: one (b, sl) per thread
  const float2* __restrict__ part = (const float2*)(ws + WS_PART);
  {
    int b = tid >> 6, sl = tid & 63;
    float2 amp = make_float2(0,0);
    #pragma unroll
    for (int g=0; g<NSG; g++){
      float2 v = part[(size_t)(b*NSG + g)*NSLOTS + slot0 + sl];
      amp.x += v.x; amp.y += v.y;
    }
    prob[b][sl] = (krow[sl] >= 0) ? fmaf(amp.x, amp.x, amp.y*amp.y) : 0.0f;
  }
  __syncthreads();

  // (C) per-b norm partial sums: one wave per b
  float* bsum = (float*)(ws + WS_BSUM);
  {
    int b = tid >> 6, l = tid & 63;
    float v = prob[b][l];
    #pragma unroll
    for (int off=32; off>0; off>>=1) v += __shfl_down(v, off);
    if (l == 0) bsum[blk*NB + b] = v;
  }

  // (D) gemm: quarter q owns 16 slots, thread owns column o
  {
    int q = tid >> 7, o = tid & 127;
    float acc[NB] = {0,0,0,0,0,0,0,0};
    int sbeg = q*16, send = sbeg + 16;
    #pragma unroll 4
    for (int sl = sbeg; sl < send; sl++){
      int kr = krow[sl]; if (kr < 0) kr = 0;   // prob already 0 for pads
      float wv = wgt[(size_t)kr * OUTS + o];
      #pragma unroll
      for (int b=0;b<NB;b++) acc[b] = fmaf(prob[b][sl], wv, acc[b]);
    }
    #pragma unroll
    for (int b=0;b<NB;b++) hacc[q][b][o] = acc[b];
  }
  __syncthreads();

  // (E) combine quarters -> pout
  float* pout = (float*)(ws + WS_POUT);
  for (int idx = tid; idx < NB*OUTS; idx += 512){
    float s = hacc[0][0][idx] + hacc[1][0][idx] + hacc[2][0][idx] + hacc[3][0][idx];
    pout[(size_t)blk*(NB*OUTS) + idx] = s;
  }
}

// ---------------- K4: final reduce: out = (sum pout)/(sum bsum) + bias ----
// grid NB x 256 threads.
__global__ __launch_bounds__(256) void k_final(
    const float* __restrict__ bias, const char* __restrict__ ws,
    float* __restrict__ out)
{
  const float* __restrict__ pout = (const float*)(ws + WS_POUT);
  const float* __restrict__ bsum = (const float*)(ws + WS_BSUM);
  __shared__ float accs[2][OUTS];
  __shared__ float wred[4];
  int tid = threadIdx.x, b = blockIdx.x;
  // norm: block-reduce of 206 bsum entries
  float v = 0.0f;
  for (int j = tid; j < NPGBLK; j += 256) v += bsum[j*NB + b];
  #pragma unroll
  for (int off=32; off>0; off>>=1) v += __shfl_down(v, off);
  if ((tid & 63) == 0) wred[tid >> 6] = v;
  // pout halves
  int o = tid & 127, half = tid >> 7;
  float a = 0.0f;
  for (int s = half; s < NPGBLK; s += 2) a += pout[(size_t)s*(NB*OUTS) + b*OUTS + o];
  accs[half][o] = a;
  __syncthreads();
  if (tid < OUTS){
    float sum = wred[0] + wred[1] + wred[2] + wred[3];
    out[b*OUTS + tid] = (accs[0][tid] + accs[1][tid]) / sum + bias[tid];
  }
}

// ---------------- launch ----------------
extern "C" void kernel_launch(void* const* d_in, const int* in_sizes, int n_in,
                              void* d_out, int out_size, void* d_ws, size_t ws_size,
                              hipStream_t stream) {
  const float* x    = (const float*)d_in[0];
  const float* th1  = (const float*)d_in[1];
  const float* th2  = (const float*)d_in[2];
  const float* mr   = (const float*)d_in[3];
  const float* mi   = (const float*)d_in[4];
  const float* wgt  = (const float*)d_in[5];
  const float* bias = (const float*)d_in[6];
  const int*   rows = (const int*)d_in[7];
  float* out = (float*)d_out;
  char* ws = (char*)d_ws;

  k_setup<<<NB + (NSTATES + 255)/256, 256, 0, stream>>>(x, th1, th2, mr, mi, rows, ws);
  k_main<<<NB*NSG*NTG, 256, 0, stream>>>(ws);
  k_pg<<<NPGBLK, 512, 0, stream>>>(wgt, ws);
  k_final<<<NB, 256, 0, stream>>>(bias, ws, out);
}